// Round 5
// baseline (383.957 us; speedup 1.0000x reference)
//
#include <hip/hip_runtime.h>

#define B_      8
#define C_      64
#define T_      32
#define HW_     3136        // 56*56
#define HW4_    784         // HW_/4 (float4 units)
#define PLANE_  (T_ * HW_)  // 100352 floats per (b,c) plane
#define NPC_    802816.0    // B_*T_*HW_ per-channel element count
#define EPS_    1e-5
#define BLK_    512
#define TAIL_   (HW4_ - BLK_)   // 272 active lanes for the second position

// native clang vector type: required by __builtin_nontemporal_* (HIP float4
// is a struct and is rejected). Same 16-byte layout as float4.
typedef float f32x4 __attribute__((ext_vector_type(4)));

// rp[t] = 6*(x[t]-x[t-6]) + 4*(x[t-1]-x[t-5]) + 2*(x[t-2]-x[t-4])
__device__ __forceinline__ float rp_tap(float a0, float a1, float a2,
                                        float a4, float a5, float a6) {
    return 6.f * (a0 - a6) + 4.f * (a1 - a5) + 2.f * (a2 - a4);
}

__device__ __forceinline__ float rp_tap4_sq(const f32x4& a0, const f32x4& a1,
                                            const f32x4& a2, const f32x4& a4,
                                            const f32x4& a5, const f32x4& a6,
                                            float& s, float& q) {
#pragma unroll
    for (int j = 0; j < 4; ++j) {
        float r = rp_tap(a0[j], a1[j], a2[j], a4[j], a5[j], a6[j]);
        s += r;
        q += r * r;
    }
    return 0.f;
}

// ---------------- Pass 1: FIR + per-plane (sum, sumsq) -> ws slot -----------
// One block per (b,c) plane. Per t-step the block reads a full contiguous
// 12.5 KB row; rows are adjacent in t -> each block streams its 401 KB plane
// sequentially (DRAM-friendly), vs the old 3584x interleaved 2 KB granules.
__global__ __launch_bounds__(BLK_, 2) void datt_pass1(
    const float* __restrict__ x, double2* __restrict__ part)
{
    const int bc  = blockIdx.x;              // b*C_ + c
    const int tid = threadIdx.x;
    const bool act1 = tid < TAIL_;           // second position in-bounds?

    const f32x4* xp = (const f32x4*)(x + (size_t)bc * PLANE_);

    f32x4 w0[7], w1[7];
#pragma unroll
    for (int k = 0; k < 7; ++k) { w0[k] = (f32x4)(0.f); w1[k] = (f32x4)(0.f); }

    float s = 0.f, q = 0.f;
#pragma unroll
    for (int t = 0; t < T_; ++t) {
        const int row = t * HW4_;
        f32x4 x0 = xp[row + tid];
        f32x4 x1 = act1 ? xp[row + BLK_ + tid] : (f32x4)(0.f);
        w0[t % 7] = x0;
        w1[t % 7] = x1;
        rp_tap4_sq(x0, w0[(t + 6) % 7], w0[(t + 5) % 7],
                       w0[(t + 3) % 7], w0[(t + 2) % 7], w0[(t + 1) % 7], s, q);
        rp_tap4_sq(x1, w1[(t + 6) % 7], w1[(t + 5) % 7],
                       w1[(t + 3) % 7], w1[(t + 2) % 7], w1[(t + 1) % 7], s, q);
    }
#pragma unroll
    for (int off = 32; off; off >>= 1) {
        s += __shfl_down(s, off);
        q += __shfl_down(q, off);
    }
    __shared__ double ls[8], lq[8];
    const int wid  = tid >> 6;
    const int lane = tid & 63;
    if (lane == 0) { ls[wid] = (double)s; lq[wid] = (double)q; }
    __syncthreads();
    if (tid == 0) {
        double S = 0.0, Q = 0.0;
#pragma unroll
        for (int i = 0; i < 8; ++i) { S += ls[i]; Q += lq[i]; }
        part[bc] = make_double2(S, Q);
    }
}

// ------- Pass 2: reduce channel stats + FIR + BN + ReLU + gate + write ------
// Same plane-per-block streaming. x loads caching (L3 hit from pass 1);
// out stores non-temporal so the write stream never evicts x from L3.
__global__ __launch_bounds__(BLK_, 2) void datt_pass2(
    const float* __restrict__ x,
    const double2* __restrict__ part,
    const float* __restrict__ gamma,
    const float* __restrict__ beta,
    const float* __restrict__ rpw,
    float* __restrict__ out)
{
    const int bc  = blockIdx.x;
    const int c   = bc & (C_ - 1);
    const int tid = threadIdx.x;
    const bool act1 = tid < TAIL_;

    __shared__ float lss[2];   // scale, shift

    if (tid < 64) {
        double s = 0.0, q = 0.0;
        if (tid < B_) {                       // 8 per-plane partials
            double2 p = part[tid * C_ + c];
            s = p.x; q = p.y;
        }
#pragma unroll
        for (int off = 4; off; off >>= 1) {
            s += __shfl_down(s, off);
            q += __shfl_down(q, off);
        }
        if (tid == 0) {
            double mean = s / NPC_;
            double var  = q / NPC_ - mean * mean;
            float rstd  = (float)(1.0 / sqrt(var + EPS_));
            float sc    = gamma[c] * rstd;
            lss[0] = sc;
            lss[1] = beta[c] - (float)mean * sc;
        }
    }
    __syncthreads();

    const float sc = lss[0];
    const float sh = lss[1];
    const float r1 = rpw[1];
    const float A  = rpw[0] + r1;        // out = x * (A + r1*y)

    const f32x4* xp = (const f32x4*)(x   + (size_t)bc * PLANE_);
    f32x4*       op = (f32x4*)      (out + (size_t)bc * PLANE_);

    f32x4 w0[7], w1[7];
#pragma unroll
    for (int k = 0; k < 7; ++k) { w0[k] = (f32x4)(0.f); w1[k] = (f32x4)(0.f); }

#pragma unroll
    for (int t = 0; t < T_; ++t) {
        const int row = t * HW4_;
        f32x4 x0 = xp[row + tid];
        f32x4 x1 = act1 ? xp[row + BLK_ + tid] : (f32x4)(0.f);
        w0[t % 7] = x0;
        w1[t % 7] = x1;

        f32x4 o0, o1;
        {
            const f32x4 a1 = w0[(t + 6) % 7], a2 = w0[(t + 5) % 7];
            const f32x4 a4 = w0[(t + 3) % 7], a5 = w0[(t + 2) % 7];
            const f32x4 a6 = w0[(t + 1) % 7];
#pragma unroll
            for (int j = 0; j < 4; ++j) {
                float yj = fmaxf(fmaf(rp_tap(x0[j], a1[j], a2[j], a4[j], a5[j], a6[j]),
                                      sc, sh), 0.f);
                o0[j] = x0[j] * fmaf(r1, yj, A);
            }
        }
        {
            const f32x4 a1 = w1[(t + 6) % 7], a2 = w1[(t + 5) % 7];
            const f32x4 a4 = w1[(t + 3) % 7], a5 = w1[(t + 2) % 7];
            const f32x4 a6 = w1[(t + 1) % 7];
#pragma unroll
            for (int j = 0; j < 4; ++j) {
                float yj = fmaxf(fmaf(rp_tap(x1[j], a1[j], a2[j], a4[j], a5[j], a6[j]),
                                      sc, sh), 0.f);
                o1[j] = x1[j] * fmaf(r1, yj, A);
            }
        }
        __builtin_nontemporal_store(o0, &op[row + tid]);
        if (act1)
            __builtin_nontemporal_store(o1, &op[row + BLK_ + tid]);
    }
}

extern "C" void kernel_launch(void* const* d_in, const int* in_sizes, int n_in,
                              void* d_out, int out_size, void* d_ws, size_t ws_size,
                              hipStream_t stream) {
    const float* x     = (const float*)d_in[0];
    const float* gamma = (const float*)d_in[1];
    const float* beta  = (const float*)d_in[2];
    const float* rpw   = (const float*)d_in[3];
    // d_in[4] is w == 7, hard-coded.
    float* out = (float*)d_out;

    double2* part = (double2*)d_ws;      // B_*C_ = 512 slots, 8 KB

    datt_pass1<<<dim3(B_ * C_), BLK_, 0, stream>>>(x, part);
    datt_pass2<<<dim3(B_ * C_), BLK_, 0, stream>>>(x, part, gamma, beta, rpw, out);
}